// Round 28
// baseline (73.460 us; speedup 1.0000x reference)
//
#include <hip/hip_runtime.h>
#include <stdint.h>

typedef __attribute__((ext_vector_type(8))) short bf16x8;
typedef __attribute__((ext_vector_type(4))) float f32x4;

static constexpr int O1_ELEMS    = 512*3*3*128*128;   // 75497472 floats
static constexpr int WB2_FLOATS  = 1048576;           // 4 MB bf16 wb2[a][k][b]
static constexpr size_t SCRATCH_BYTES = (size_t)WB2_FLOATS*4;   // 4 MB (wb2 only)
static constexpr int NTILES      = 4608;              // 512*9 tiles (128x128 f32)
static constexpr int SKIP_TILES  = 64;                // fallback: 64*64KB = 4 MB
static constexpr int NCONV       = 512;               // conv blocks (128 a x 4 slices)
static constexpr int S1          = 1280;              // k1 stream-tile share
static constexpr int NCB         = 384;               // 48 mt x 8 k-slices
static constexpr int TAIL        = 2;                 // tiles per comp block (tail-fill)

__device__ inline unsigned short f32_to_bf16(float f) {
    union { float f; uint32_t u; } v; v.f = f;
    uint32_t r = v.u + 0x7FFF + ((v.u >> 16) & 1);    // RNE
    return (unsigned short)(r >> 16);
}

__device__ inline bf16x8 bf16x8_from_f32(const float* p) {
    float4 v0 = *(const float4*)p;
    float4 v1 = *(const float4*)(p + 4);
    union { bf16x8 v; unsigned short s[8]; } u;
    u.s[0] = f32_to_bf16(v0.x); u.s[1] = f32_to_bf16(v0.y);
    u.s[2] = f32_to_bf16(v0.z); u.s[3] = f32_to_bf16(v0.w);
    u.s[4] = f32_to_bf16(v1.x); u.s[5] = f32_to_bf16(v1.y);
    u.s[6] = f32_to_bf16(v1.z); u.s[7] = f32_to_bf16(v1.w);
    return u.v;
}

// ---- one 128x128 out1 tile (lanes t in [0,256)), nontemporal stores ----
__device__ inline void write_tile(int tile, const float* __restrict__ x,
                                  const float* __restrict__ y,
                                  float* __restrict__ out1, int t) {
    const f32x4* y4 = (const f32x4*)y;
    f32x4* o4 = (f32x4*)out1;
    const int b4 = t & 31, a0 = t >> 5;               // col f4, row group 0..7
    int n  = tile / 9;
    int ij = tile - n * 9;
    int i  = ij / 3, j = ij - i * 3;
    f32x4 yv = y4[(n * 3 + j) * 32 + b4];
    const float* xrow = x + (n * 3 + i) * 128;
    f32x4* dst = o4 + (size_t)tile * 4096 + a0 * 32 + b4;
    #pragma unroll
    for (int p = 0; p < 16; ++p) {
        float xs = xrow[p * 8 + a0];                  // wave-broadcast load
        f32x4 r = yv * xs;
        __builtin_nontemporal_store(r, dst);          // keep L2 for compute data
        dst += 256;                                   // 8 rows * 32 f4
    }
}

// ---- conv role (R25): blk in [0,512) = (a, 32-b-row slice) ----
__device__ inline void conv_role(int blk, int t, const float* __restrict__ w,
                                 unsigned short* __restrict__ wb2, char* smem) {
    unsigned short (*lt)[132] = (unsigned short (*)[132])smem;   // [32][132]
    const int a  = blk >> 2;
    const int b0 = (blk & 3) * 32;
    const float4* src = (const float4*)(w + (size_t)a * 16384 + (size_t)b0 * 128);
    #pragma unroll
    for (int it = 0; it < 4; ++it) {                   // 1024 f4 = 32 rows x 128 k
        int fidx = it * 256 + t;
        float4 v = src[fidx];
        int b = fidx >> 5, k4 = fidx & 31;
        unsigned short* d = &lt[b][k4 * 4];
        d[0] = f32_to_bf16(v.x); d[1] = f32_to_bf16(v.y);
        d[2] = f32_to_bf16(v.z); d[3] = f32_to_bf16(v.w);
    }
    __syncthreads();
    #pragma unroll
    for (int it = 0; it < 2; ++it) {
        const int k = it * 64 + (t >> 2);              // 0..127
        const int q = t & 3;                           // 8-b sub-slice
        uint32_t pk[4];
        #pragma unroll
        for (int qq = 0; qq < 4; ++qq) {
            uint32_t lo = lt[q * 8 + qq * 2][k];
            uint32_t hi = lt[q * 8 + qq * 2 + 1][k];
            pk[qq] = lo | (hi << 16);
        }
        uint4 vv = {pk[0], pk[1], pk[2], pk[3]};
        *(uint4*)(wb2 + (size_t)a * 16384 + (size_t)k * 128 + b0 + q * 8) = vv;
    }
}

// ---- comp role: 32m x 16k; 4 waves split the 128 a's; unroll 4 for latency ----
__device__ inline void comp_role(int cb, int tid, float alpha,
                                 const float* __restrict__ x,
                                 const float* __restrict__ y,
                                 const unsigned short* __restrict__ wb2,
                                 float* __restrict__ out2, char* smem) {
    float (*xsh)[3][32] = (float (*)[3][32])smem;      // [128a][3][32m] 48 KB
    const int ksl = cb & 7;                // k-slice: cols [ksl*16, +16)
    const int mt  = cb >> 3;               // 0..47: rows [mt*32, +32)
    const int l   = tid & 63;
    const int wv  = tid >> 6;              // 0..3 -> a-range [wv*32, +32)
    const int l15 = l & 15, lg = l >> 4;

    bf16x8 afrag[2][4];                    // rows mt*32 + Mt*16 + l15
    #pragma unroll
    for (int Mt = 0; Mt < 2; ++Mt)
        #pragma unroll
        for (int ks = 0; ks < 4; ++ks)
            afrag[Mt][ks] = bf16x8_from_f32(
                y + (size_t)(mt * 32 + Mt * 16 + l15) * 128 + ks * 32 + lg * 8);

    #pragma unroll
    for (int p = 0; p < 48; ++p) {         // x tile: 128a x 3 x 32m
        int e = tid + p * 256;
        int aa = e / 96, r = e - aa * 96, i = r >> 5, mm = r & 31;
        int n = (mt * 32 + mm) / 3;
        xsh[aa][i][mm] = x[n * 384 + i * 128 + aa];
    }
    __syncthreads();

    float acc2[3][2][4] = {};
    const unsigned short* wbase =
        wb2 + (size_t)(ksl * 16 + l15) * 128 + lg * 8;

    #pragma unroll 4
    for (int ac = 0; ac < 32; ++ac) {      // unroll 4: 16 loads in flight
        const int a = wv * 32 + ac;
        const unsigned short* wp = wbase + (size_t)a * 16384;
        bf16x8 bf0 = *(const bf16x8*)(wp);
        bf16x8 bf1 = *(const bf16x8*)(wp + 32);
        bf16x8 bf2 = *(const bf16x8*)(wp + 64);
        bf16x8 bf3 = *(const bf16x8*)(wp + 96);

        f32x4 t0 = {0.f, 0.f, 0.f, 0.f}, t1 = {0.f, 0.f, 0.f, 0.f};
        t0 = __builtin_amdgcn_mfma_f32_16x16x32_bf16(afrag[0][0], bf0, t0, 0, 0, 0);
        t1 = __builtin_amdgcn_mfma_f32_16x16x32_bf16(afrag[1][0], bf0, t1, 0, 0, 0);
        t0 = __builtin_amdgcn_mfma_f32_16x16x32_bf16(afrag[0][1], bf1, t0, 0, 0, 0);
        t1 = __builtin_amdgcn_mfma_f32_16x16x32_bf16(afrag[1][1], bf1, t1, 0, 0, 0);
        t0 = __builtin_amdgcn_mfma_f32_16x16x32_bf16(afrag[0][2], bf2, t0, 0, 0, 0);
        t1 = __builtin_amdgcn_mfma_f32_16x16x32_bf16(afrag[1][2], bf2, t1, 0, 0, 0);
        t0 = __builtin_amdgcn_mfma_f32_16x16x32_bf16(afrag[0][3], bf3, t0, 0, 0, 0);
        t1 = __builtin_amdgcn_mfma_f32_16x16x32_bf16(afrag[1][3], bf3, t1, 0, 0, 0);

        #pragma unroll
        for (int i = 0; i < 3; ++i) {
            float4 xv0 = *(const float4*)&xsh[a][i][lg * 4];
            float4 xv1 = *(const float4*)&xsh[a][i][16 + lg * 4];
            acc2[i][0][0] += xv0.x * t0[0]; acc2[i][0][1] += xv0.y * t0[1];
            acc2[i][0][2] += xv0.z * t0[2]; acc2[i][0][3] += xv0.w * t0[3];
            acc2[i][1][0] += xv1.x * t1[0]; acc2[i][1][1] += xv1.y * t1[1];
            acc2[i][1][2] += xv1.z * t1[2]; acc2[i][1][3] += xv1.w * t1[3];
        }
    }

    // cross-wave reduce: red[wv][lane][24] (24 KB, reuses xsh region)
    __syncthreads();                       // all waves done reading xsh
    float* red = (float*)smem;
    const int base = (wv * 64 + l) * 24;
    #pragma unroll
    for (int i = 0; i < 3; ++i)
        #pragma unroll
        for (int Mt = 0; Mt < 2; ++Mt)
            #pragma unroll
            for (int r = 0; r < 4; ++r)
                red[base + (i * 2 + Mt) * 4 + r] = acc2[i][Mt][r];
    __syncthreads();

    if (wv == 0) {
        #pragma unroll
        for (int i = 0; i < 3; ++i)
            #pragma unroll
            for (int Mt = 0; Mt < 2; ++Mt)
                #pragma unroll
                for (int r = 0; r < 4; ++r) {
                    const int idx = (i * 2 + Mt) * 4 + r;
                    float s = acc2[i][Mt][r]
                            + red[(64 + l) * 24 + idx]
                            + red[(128 + l) * 24 + idx]
                            + red[(192 + l) * 24 + idx];
                    int m = mt * 32 + Mt * 16 + lg * 4 + r;
                    int n = m / 3, j = m - 3 * n;
                    out2[((size_t)(n * 3 + i) * 3 + j) * 128 + ksl * 16 + l15] =
                        alpha * s;
                }
    }
}

// ---- K1: conv (0..NCONV) || stream tiles [t0, t0+S1) ----
__global__ __launch_bounds__(256) void k1_kernel(const float* __restrict__ w,
                                                 const float* __restrict__ x,
                                                 const float* __restrict__ y,
                                                 unsigned short* __restrict__ wb2,
                                                 float* __restrict__ out1, int t0) {
    __shared__ __align__(16) char smem[8448];
    const int b = (int)blockIdx.x;
    if (b < NCONV) { conv_role(b, (int)threadIdx.x, w, wb2, smem); return; }
    write_tile(t0 + b - NCONV, x, y, out1, (int)threadIdx.x);
}

// ---- K2: comp (0..NCB) + TAIL tiles each || pure streamers for the rest ----
__global__ __launch_bounds__(256) void k2_kernel(const float* __restrict__ a_s,
                                                 const float* __restrict__ x,
                                                 const float* __restrict__ y,
                                                 const unsigned short* __restrict__ wb2,
                                                 float* __restrict__ out1,
                                                 float* __restrict__ out2,
                                                 int t0, int tailbase) {
    __shared__ __align__(16) char smem[49152];
    const int b = (int)blockIdx.x;
    const int t = (int)threadIdx.x;
    if (b < NCB) {
        comp_role(b, t, 0.75f * a_s[0], x, y, wb2, out2, smem);
        #pragma unroll
        for (int q = 0; q < TAIL; ++q)     // tail-fill: keep HBM busy to the end
            write_tile(tailbase + b * TAIL + q, x, y, out1, t);
        return;
    }
    write_tile(t0 + S1 + (b - NCB), x, y, out1, t);
}

// ---- finish (fallback-scratch only): rewrite scratch-head tiles ----
__global__ __launch_bounds__(256) void finish_kernel(const float* __restrict__ x,
                                                     const float* __restrict__ y,
                                                     float* __restrict__ out1) {
    write_tile((int)blockIdx.x, x, y, out1, (int)threadIdx.x);
}

extern "C" void kernel_launch(void* const* d_in, const int* in_sizes, int n_in,
                              void* d_out, int out_size, void* d_ws, size_t ws_size,
                              hipStream_t stream) {
    const float* w  = (const float*)d_in[0];
    const float* as = (const float*)d_in[1];
    const float* x  = (const float*)d_in[2];
    const float* y  = (const float*)d_in[3];
    float* out1 = (float*)d_out;
    float* out2 = out1 + O1_ELEMS;

    const bool have_ws = (ws_size >= SCRATCH_BYTES);
    unsigned short* wb2 = have_ws ? (unsigned short*)d_ws : (unsigned short*)out1;
    const int t0 = have_ws ? 0 : SKIP_TILES;
    const int s2 = NTILES - t0 - S1;               // k2 tiles total
    const int s2pure = s2 - NCB * TAIL;            // pure-streamer tiles
    const int tailbase = t0 + S1 + s2pure;         // comp tail-fill range start

    k1_kernel<<<NCONV + S1, 256, 0, stream>>>(w, x, y, wb2, out1, t0);
    k2_kernel<<<NCB + s2pure, 256, 0, stream>>>(as, x, y, wb2, out1, out2, t0, tailbase);
    if (!have_ws)
        finish_kernel<<<SKIP_TILES, 256, 0, stream>>>(x, y, out1);
}

// Round 29
// 68.786 us; speedup vs baseline: 1.0679x; 1.0679x over previous
//
#include <hip/hip_runtime.h>
#include <stdint.h>

typedef __attribute__((ext_vector_type(8))) short bf16x8;
typedef __attribute__((ext_vector_type(4))) float f32x4;

static constexpr int O1_ELEMS    = 512*3*3*128*128;   // 75497472 floats
static constexpr int WB2_FLOATS  = 1048576;           // 4 MB bf16 wb2[a][k][b]
static constexpr size_t SCRATCH_BYTES = (size_t)WB2_FLOATS*4;   // 4 MB (wb2 only)
static constexpr int NTILES      = 4608;              // 512*9 tiles (128x128 f32)
static constexpr int SKIP_TILES  = 64;                // fallback: 64*64KB = 4 MB
static constexpr int NCONV       = 512;               // conv blocks (128 a x 4 slices)
static constexpr int S1          = 1280;              // k1 stream-tile share
static constexpr int NCB         = 384;               // 48 mt x 8 k-slices

__device__ inline unsigned short f32_to_bf16(float f) {
    union { float f; uint32_t u; } v; v.f = f;
    uint32_t r = v.u + 0x7FFF + ((v.u >> 16) & 1);    // RNE
    return (unsigned short)(r >> 16);
}

__device__ inline bf16x8 bf16x8_from_f32(const float* p) {
    float4 v0 = *(const float4*)p;
    float4 v1 = *(const float4*)(p + 4);
    union { bf16x8 v; unsigned short s[8]; } u;
    u.s[0] = f32_to_bf16(v0.x); u.s[1] = f32_to_bf16(v0.y);
    u.s[2] = f32_to_bf16(v0.z); u.s[3] = f32_to_bf16(v0.w);
    u.s[4] = f32_to_bf16(v1.x); u.s[5] = f32_to_bf16(v1.y);
    u.s[6] = f32_to_bf16(v1.z); u.s[7] = f32_to_bf16(v1.w);
    return u.v;
}

// ---- one 128x128 out1 tile (lanes t in [0,256)), nontemporal stores ----
__device__ inline void write_tile(int tile, const float* __restrict__ x,
                                  const float* __restrict__ y,
                                  float* __restrict__ out1, int t) {
    const f32x4* y4 = (const f32x4*)y;
    f32x4* o4 = (f32x4*)out1;
    const int b4 = t & 31, a0 = t >> 5;               // col f4, row group 0..7
    int n  = tile / 9;
    int ij = tile - n * 9;
    int i  = ij / 3, j = ij - i * 3;
    f32x4 yv = y4[(n * 3 + j) * 32 + b4];
    const float* xrow = x + (n * 3 + i) * 128;
    f32x4* dst = o4 + (size_t)tile * 4096 + a0 * 32 + b4;
    #pragma unroll
    for (int p = 0; p < 16; ++p) {
        float xs = xrow[p * 8 + a0];                  // wave-broadcast load
        f32x4 r = yv * xs;
        __builtin_nontemporal_store(r, dst);          // keep L2 for compute data
        dst += 256;                                   // 8 rows * 32 f4
    }
}

// ---- conv role (R25): blk in [0,512) = (a, 32-b-row slice) ----
__device__ inline void conv_role(int blk, int t, const float* __restrict__ w,
                                 unsigned short* __restrict__ wb2, char* smem) {
    unsigned short (*lt)[132] = (unsigned short (*)[132])smem;   // [32][132]
    const int a  = blk >> 2;
    const int b0 = (blk & 3) * 32;
    const float4* src = (const float4*)(w + (size_t)a * 16384 + (size_t)b0 * 128);
    #pragma unroll
    for (int it = 0; it < 4; ++it) {                   // 1024 f4 = 32 rows x 128 k
        int fidx = it * 256 + t;
        float4 v = src[fidx];
        int b = fidx >> 5, k4 = fidx & 31;
        unsigned short* d = &lt[b][k4 * 4];
        d[0] = f32_to_bf16(v.x); d[1] = f32_to_bf16(v.y);
        d[2] = f32_to_bf16(v.z); d[3] = f32_to_bf16(v.w);
    }
    __syncthreads();
    #pragma unroll
    for (int it = 0; it < 2; ++it) {
        const int k = it * 64 + (t >> 2);              // 0..127
        const int q = t & 3;                           // 8-b sub-slice
        uint32_t pk[4];
        #pragma unroll
        for (int qq = 0; qq < 4; ++qq) {
            uint32_t lo = lt[q * 8 + qq * 2][k];
            uint32_t hi = lt[q * 8 + qq * 2 + 1][k];
            pk[qq] = lo | (hi << 16);
        }
        uint4 vv = {pk[0], pk[1], pk[2], pk[3]};
        *(uint4*)(wb2 + (size_t)a * 16384 + (size_t)k * 128 + b0 + q * 8) = vv;
    }
}

// ---- comp role (R23/R25-validated): 32m x 16k; 4 waves split the 128 a's ----
__device__ inline void comp_role(int cb, int tid, float alpha,
                                 const float* __restrict__ x,
                                 const float* __restrict__ y,
                                 const unsigned short* __restrict__ wb2,
                                 float* __restrict__ out2, char* smem) {
    float (*xsh)[3][32] = (float (*)[3][32])smem;      // [128a][3][32m] 48 KB
    const int ksl = cb & 7;                // k-slice: cols [ksl*16, +16)
    const int mt  = cb >> 3;               // 0..47: rows [mt*32, +32)
    const int l   = tid & 63;
    const int wv  = tid >> 6;              // 0..3 -> a-range [wv*32, +32)
    const int l15 = l & 15, lg = l >> 4;

    bf16x8 afrag[2][4];                    // rows mt*32 + Mt*16 + l15
    #pragma unroll
    for (int Mt = 0; Mt < 2; ++Mt)
        #pragma unroll
        for (int ks = 0; ks < 4; ++ks)
            afrag[Mt][ks] = bf16x8_from_f32(
                y + (size_t)(mt * 32 + Mt * 16 + l15) * 128 + ks * 32 + lg * 8);

    #pragma unroll
    for (int p = 0; p < 48; ++p) {         // x tile: 128a x 3 x 32m
        int e = tid + p * 256;
        int aa = e / 96, r = e - aa * 96, i = r >> 5, mm = r & 31;
        int n = (mt * 32 + mm) / 3;
        xsh[aa][i][mm] = x[n * 384 + i * 128 + aa];
    }
    __syncthreads();

    float acc2[3][2][4] = {};
    const unsigned short* wbase =
        wb2 + (size_t)(ksl * 16 + l15) * 128 + lg * 8;

    #pragma unroll 2
    for (int ac = 0; ac < 32; ++ac) {
        const int a = wv * 32 + ac;
        const unsigned short* wp = wbase + (size_t)a * 16384;
        bf16x8 bf0 = *(const bf16x8*)(wp);
        bf16x8 bf1 = *(const bf16x8*)(wp + 32);
        bf16x8 bf2 = *(const bf16x8*)(wp + 64);
        bf16x8 bf3 = *(const bf16x8*)(wp + 96);

        f32x4 t0 = {0.f, 0.f, 0.f, 0.f}, t1 = {0.f, 0.f, 0.f, 0.f};
        t0 = __builtin_amdgcn_mfma_f32_16x16x32_bf16(afrag[0][0], bf0, t0, 0, 0, 0);
        t1 = __builtin_amdgcn_mfma_f32_16x16x32_bf16(afrag[1][0], bf0, t1, 0, 0, 0);
        t0 = __builtin_amdgcn_mfma_f32_16x16x32_bf16(afrag[0][1], bf1, t0, 0, 0, 0);
        t1 = __builtin_amdgcn_mfma_f32_16x16x32_bf16(afrag[1][1], bf1, t1, 0, 0, 0);
        t0 = __builtin_amdgcn_mfma_f32_16x16x32_bf16(afrag[0][2], bf2, t0, 0, 0, 0);
        t1 = __builtin_amdgcn_mfma_f32_16x16x32_bf16(afrag[1][2], bf2, t1, 0, 0, 0);
        t0 = __builtin_amdgcn_mfma_f32_16x16x32_bf16(afrag[0][3], bf3, t0, 0, 0, 0);
        t1 = __builtin_amdgcn_mfma_f32_16x16x32_bf16(afrag[1][3], bf3, t1, 0, 0, 0);

        #pragma unroll
        for (int i = 0; i < 3; ++i) {
            float4 xv0 = *(const float4*)&xsh[a][i][lg * 4];
            float4 xv1 = *(const float4*)&xsh[a][i][16 + lg * 4];
            acc2[i][0][0] += xv0.x * t0[0]; acc2[i][0][1] += xv0.y * t0[1];
            acc2[i][0][2] += xv0.z * t0[2]; acc2[i][0][3] += xv0.w * t0[3];
            acc2[i][1][0] += xv1.x * t1[0]; acc2[i][1][1] += xv1.y * t1[1];
            acc2[i][1][2] += xv1.z * t1[2]; acc2[i][1][3] += xv1.w * t1[3];
        }
    }

    // cross-wave reduce: red[wv][lane][24] (24 KB, reuses xsh region)
    __syncthreads();                       // all waves done reading xsh
    float* red = (float*)smem;
    const int base = (wv * 64 + l) * 24;
    #pragma unroll
    for (int i = 0; i < 3; ++i)
        #pragma unroll
        for (int Mt = 0; Mt < 2; ++Mt)
            #pragma unroll
            for (int r = 0; r < 4; ++r)
                red[base + (i * 2 + Mt) * 4 + r] = acc2[i][Mt][r];
    __syncthreads();

    if (wv == 0) {
        #pragma unroll
        for (int i = 0; i < 3; ++i)
            #pragma unroll
            for (int Mt = 0; Mt < 2; ++Mt)
                #pragma unroll
                for (int r = 0; r < 4; ++r) {
                    const int idx = (i * 2 + Mt) * 4 + r;
                    float s = acc2[i][Mt][r]
                            + red[(64 + l) * 24 + idx]
                            + red[(128 + l) * 24 + idx]
                            + red[(192 + l) * 24 + idx];
                    int m = mt * 32 + Mt * 16 + lg * 4 + r;
                    int n = m / 3, j = m - 3 * n;
                    out2[((size_t)(n * 3 + i) * 3 + j) * 128 + ksl * 16 + l15] =
                        alpha * s;
                }
    }
}

// ---- K1: conv (0..NCONV) || stream tiles [t0, t0+S1) ----
__global__ __launch_bounds__(256) void k1_kernel(const float* __restrict__ w,
                                                 const float* __restrict__ x,
                                                 const float* __restrict__ y,
                                                 unsigned short* __restrict__ wb2,
                                                 float* __restrict__ out1, int t0) {
    __shared__ __align__(16) char smem[8448];
    const int b = (int)blockIdx.x;
    if (b < NCONV) { conv_role(b, (int)threadIdx.x, w, wb2, smem); return; }
    write_tile(t0 + b - NCONV, x, y, out1, (int)threadIdx.x);
}

// ---- K2: comp (0..NCB, direct out2) || stream tiles [t0+S1, NTILES) ----
__global__ __launch_bounds__(256) void k2_kernel(const float* __restrict__ a_s,
                                                 const float* __restrict__ x,
                                                 const float* __restrict__ y,
                                                 const unsigned short* __restrict__ wb2,
                                                 float* __restrict__ out1,
                                                 float* __restrict__ out2, int t0) {
    __shared__ __align__(16) char smem[49152];
    const int b = (int)blockIdx.x;
    const int t = (int)threadIdx.x;
    if (b < NCB) {
        comp_role(b, t, 0.75f * a_s[0], x, y, wb2, out2, smem);
        return;
    }
    write_tile(t0 + S1 + (b - NCB), x, y, out1, t);
}

// ---- finish (fallback-scratch only): rewrite scratch-head tiles ----
__global__ __launch_bounds__(256) void finish_kernel(const float* __restrict__ x,
                                                     const float* __restrict__ y,
                                                     float* __restrict__ out1) {
    write_tile((int)blockIdx.x, x, y, out1, (int)threadIdx.x);
}

extern "C" void kernel_launch(void* const* d_in, const int* in_sizes, int n_in,
                              void* d_out, int out_size, void* d_ws, size_t ws_size,
                              hipStream_t stream) {
    const float* w  = (const float*)d_in[0];
    const float* as = (const float*)d_in[1];
    const float* x  = (const float*)d_in[2];
    const float* y  = (const float*)d_in[3];
    float* out1 = (float*)d_out;
    float* out2 = out1 + O1_ELEMS;

    const bool have_ws = (ws_size >= SCRATCH_BYTES);
    unsigned short* wb2 = have_ws ? (unsigned short*)d_ws : (unsigned short*)out1;
    const int t0 = have_ws ? 0 : SKIP_TILES;
    const int s2 = NTILES - t0 - S1;       // ws: 3328; fallback: 3264

    k1_kernel<<<NCONV + S1, 256, 0, stream>>>(w, x, y, wb2, out1, t0);
    k2_kernel<<<NCB + s2, 256, 0, stream>>>(as, x, y, wb2, out1, out2, t0);
    if (!have_ws)
        finish_kernel<<<SKIP_TILES, 256, 0, stream>>>(x, y, out1);
}